// Round 1
// baseline (87.398 us; speedup 1.0000x reference)
//
#include <hip/hip_runtime.h>
#include <math.h>

#define BB 32
#define SS 2048
#define DD 1024
#define NCH 32      // chunks over S for the value pass
#define CHS 64      // S per chunk (NCH*CHS == SS)

// K1: energy[b*SS+s] = dot(enc[s,b,:], q[b,:]).  One 64-lane wave per (s,b).
__global__ __launch_bounds__(256) void energy_kernel(const float* __restrict__ q,
                                                     const float* __restrict__ enc,
                                                     float* __restrict__ energy) {
    int gid  = blockIdx.x * 256 + threadIdx.x;
    int w    = gid >> 6;          // pair index p = s*BB + b
    int lane = gid & 63;
    int b    = w & (BB - 1);
    int s    = w >> 5;
    const float4* vp = (const float4*)(enc + (size_t)w * DD);
    const float4* qp = (const float4*)(q + (size_t)b * DD);
    float acc = 0.f;
#pragma unroll
    for (int k = 0; k < 4; ++k) {
        float4 v  = vp[lane + k * 64];
        float4 qq = qp[lane + k * 64];
        acc += v.x * qq.x + v.y * qq.y + v.z * qq.z + v.w * qq.w;
    }
#pragma unroll
    for (int off = 32; off > 0; off >>= 1)
        acc += __shfl_down(acc, off, 64);
    if (lane == 0) energy[b * SS + s] = acc;
}

// K2: per-b softmax over S. scores[b*SS+s] = exp(e-m)/sum.
__global__ __launch_bounds__(256) void softmax_kernel(const float* __restrict__ energy,
                                                      float* __restrict__ scores) {
    int b   = blockIdx.x;
    int tid = threadIdx.x;
    __shared__ float red[8];
    float e[8];
    float m = -1e30f;
#pragma unroll
    for (int k = 0; k < 8; ++k) {
        e[k] = energy[b * SS + k * 256 + tid];
        m = fmaxf(m, e[k]);
    }
#pragma unroll
    for (int off = 32; off > 0; off >>= 1)
        m = fmaxf(m, __shfl_xor(m, off, 64));
    int wid = tid >> 6;
    if ((tid & 63) == 0) red[wid] = m;
    __syncthreads();
    m = fmaxf(fmaxf(red[0], red[1]), fmaxf(red[2], red[3]));
    float p[8], l = 0.f;
#pragma unroll
    for (int k = 0; k < 8; ++k) { p[k] = expf(e[k] - m); l += p[k]; }
#pragma unroll
    for (int off = 32; off > 0; off >>= 1)
        l += __shfl_xor(l, off, 64);
    if ((tid & 63) == 0) red[4 + wid] = l;
    __syncthreads();
    l = red[4] + red[5] + red[6] + red[7];
    float inv = 1.f / l;
#pragma unroll
    for (int k = 0; k < 8; ++k)
        scores[b * SS + k * 256 + tid] = p[k] * inv;
}

// K3: partial[bc][d] = sum_{s in chunk c} scores[b,s] * enc[s,b,d]
__global__ __launch_bounds__(256) void pv_partial(const float* __restrict__ enc,
                                                  const float* __restrict__ scores,
                                                  float* __restrict__ partial) {
    int bc  = blockIdx.x;       // b*NCH + c
    int b   = bc >> 5;
    int c   = bc & (NCH - 1);
    int tid = threadIdx.x;
    __shared__ float w[CHS];
    if (tid < CHS) w[tid] = scores[b * SS + c * CHS + tid];
    __syncthreads();
    float4 acc = {0.f, 0.f, 0.f, 0.f};
    int s0 = c * CHS;
    for (int i = 0; i < CHS; ++i) {
        int s = s0 + i;
        const float4* vp = (const float4*)(enc + (size_t)(s * BB + b) * DD);
        float4 v = vp[tid];
        float ws = w[i];
        acc.x += ws * v.x; acc.y += ws * v.y; acc.z += ws * v.z; acc.w += ws * v.w;
    }
    float4* pp = (float4*)(partial + (size_t)bc * DD);
    pp[tid] = acc;
}

// K4: out[b*DD+d] = sum_c partial[(b*NCH+c)*DD + d]
__global__ __launch_bounds__(256) void reduce_kernel(const float* __restrict__ partial,
                                                     float* __restrict__ out) {
    int idx = blockIdx.x * 256 + threadIdx.x;   // 0..BB*DD-1
    int b   = idx >> 10;
    int d   = idx & (DD - 1);
    float acc = 0.f;
#pragma unroll
    for (int c = 0; c < NCH; ++c)
        acc += partial[(size_t)(b * NCH + c) * DD + d];
    out[idx] = acc;
}

extern "C" void kernel_launch(void* const* d_in, const int* in_sizes, int n_in,
                              void* d_out, int out_size, void* d_ws, size_t ws_size,
                              hipStream_t stream) {
    const float* q   = (const float*)d_in[0];   // (1,B,D)
    const float* enc = (const float*)d_in[1];   // (S,B,D)
    float* out    = (float*)d_out;
    float* values = out;             // (B,D)  = 32768 floats
    float* scores = out + BB * DD;   // (B,S)  = 65536 floats
    float* energy  = (float*)d_ws;             // BB*SS floats
    float* partial = energy + BB * SS;         // BB*NCH*DD floats (4 MiB)

    energy_kernel<<<(BB * SS * 64) / 256, 256, 0, stream>>>(q, enc, energy);
    softmax_kernel<<<BB, 256, 0, stream>>>(energy, scores);
    pv_partial<<<BB * NCH, 256, 0, stream>>>(enc, scores, partial);
    reduce_kernel<<<(BB * DD) / 256, 256, 0, stream>>>(partial, values);
}

// Round 2
// 53.849 us; speedup vs baseline: 1.6230x; 1.6230x over previous
//
#include <hip/hip_runtime.h>
#include <math.h>

#define BB 32
#define SS 2048
#define DD 1024
#define NCH 32      // S-chunks per b
#define CHS 64      // rows per chunk (NCH*CHS == SS)

// ws layout (floats):
//   energy : BB*SS          (256 KiB)
//   partial: BB*NCH*DD      (4 MiB)
//   ml     : BB*NCH*2       (8 KiB)   per-chunk running (m, l)
//   ML     : BB*2           (256 B)   per-b global (M, L)

// K1: fused energy + online-softmax PV over one S-chunk.
// One block per (b, chunk): 256 threads, thread owns float4 of D.
__global__ __launch_bounds__(256) void fused_pass(const float* __restrict__ q,
                                                  const float* __restrict__ enc,
                                                  float* __restrict__ energy,
                                                  float* __restrict__ partial,
                                                  float* __restrict__ ml) {
    int bc   = blockIdx.x;            // b*NCH + c
    int b    = bc >> 5;               // NCH = 32
    int c    = bc & (NCH - 1);
    int tid  = threadIdx.x;
    int wid  = tid >> 6;
    int lane = tid & 63;
    __shared__ float red[2][4];

    float4 qv = ((const float4*)(q + (size_t)b * DD))[tid];

    int s0 = c * CHS;
    const float4* base = (const float4*)enc;
    const size_t rowstride = (size_t)BB * DD / 4;        // float4 units per s
    size_t idx = (size_t)(s0 * BB + b) * (DD / 4) + tid;

    float m = -1e30f, l = 0.f;
    float4 acc = {0.f, 0.f, 0.f, 0.f};
    float4 v = base[idx];

    for (int i = 0; i < CHS; ++i) {
        float4 vn = {0.f, 0.f, 0.f, 0.f};
        if (i + 1 < CHS) vn = base[idx + (size_t)(i + 1) * rowstride];  // prefetch

        float pd = v.x * qv.x + v.y * qv.y + v.z * qv.z + v.w * qv.w;
#pragma unroll
        for (int off = 32; off > 0; off >>= 1)
            pd += __shfl_xor(pd, off, 64);
        if (lane == 0) red[i & 1][wid] = pd;
        __syncthreads();
        float e = red[i & 1][0] + red[i & 1][1] + red[i & 1][2] + red[i & 1][3];

        if (tid == 0) energy[b * SS + s0 + i] = e;

        float mn    = fmaxf(m, e);
        float scale = __expf(m - mn);
        float p     = __expf(e - mn);
        l = l * scale + p;
        acc.x = acc.x * scale + p * v.x;
        acc.y = acc.y * scale + p * v.y;
        acc.z = acc.z * scale + p * v.z;
        acc.w = acc.w * scale + p * v.w;
        m = mn;
        v = vn;
    }

    ((float4*)(partial + (size_t)bc * DD))[tid] = acc;
    if (tid == 0) { ml[bc * 2] = m; ml[bc * 2 + 1] = l; }
}

// K2: merge NCH chunk partials per b; write values and (M, L).
__global__ __launch_bounds__(256) void merge_kernel(const float* __restrict__ partial,
                                                    const float* __restrict__ ml,
                                                    float* __restrict__ values,
                                                    float* __restrict__ ML) {
    int b   = blockIdx.x;
    int tid = threadIdx.x;
    __shared__ float sw[NCH];
    __shared__ float Lsh, Msh;

    if (tid == 0) {
        float M = -1e30f;
        for (int c2 = 0; c2 < NCH; ++c2) M = fmaxf(M, ml[(b * NCH + c2) * 2]);
        float L = 0.f;
        for (int c2 = 0; c2 < NCH; ++c2) {
            float w = __expf(ml[(b * NCH + c2) * 2] - M);
            sw[c2] = w;
            L += w * ml[(b * NCH + c2) * 2 + 1];
        }
        Msh = M; Lsh = L;
        ML[b * 2] = M; ML[b * 2 + 1] = L;
    }
    __syncthreads();

    float4 acc = {0.f, 0.f, 0.f, 0.f};
    for (int c2 = 0; c2 < NCH; ++c2) {
        float w = sw[c2];
        float4 p = ((const float4*)(partial + (size_t)(b * NCH + c2) * DD))[tid];
        acc.x += w * p.x; acc.y += w * p.y; acc.z += w * p.z; acc.w += w * p.w;
    }
    float inv = 1.f / Lsh;
    acc.x *= inv; acc.y *= inv; acc.z *= inv; acc.w *= inv;
    ((float4*)(values + (size_t)b * DD))[tid] = acc;
}

// K3: scores[b,s] = exp(energy - M_b) / L_b
__global__ __launch_bounds__(256) void scores_kernel(const float* __restrict__ energy,
                                                     const float* __restrict__ ML,
                                                     float* __restrict__ scores) {
    int idx = blockIdx.x * 256 + threadIdx.x;   // 0..BB*SS-1
    int b   = idx >> 11;                        // SS = 2048
    float M = ML[b * 2], L = ML[b * 2 + 1];
    scores[idx] = __expf(energy[idx] - M) / L;
}

extern "C" void kernel_launch(void* const* d_in, const int* in_sizes, int n_in,
                              void* d_out, int out_size, void* d_ws, size_t ws_size,
                              hipStream_t stream) {
    const float* q   = (const float*)d_in[0];   // (1,B,D)
    const float* enc = (const float*)d_in[1];   // (S,B,D)
    float* out    = (float*)d_out;
    float* values = out;                        // (B,D)
    float* scores = out + BB * DD;              // (B,S)

    float* energy  = (float*)d_ws;              // BB*SS
    float* partial = energy + BB * SS;          // BB*NCH*DD
    float* ml      = partial + (size_t)BB * NCH * DD;  // BB*NCH*2
    float* ML      = ml + BB * NCH * 2;                // BB*2

    fused_pass<<<BB * NCH, 256, 0, stream>>>(q, enc, energy, partial, ml);
    merge_kernel<<<BB, 256, 0, stream>>>(partial, ml, values, ML);
    scores_kernel<<<(BB * SS) / 256, 256, 0, stream>>>(energy, ML, scores);
}